// Round 10
// baseline (66.874 us; speedup 1.0000x reference)
//
#include <hip/hip_runtime.h>
#include <hip/hip_bf16.h>

// Problem constants (fixed by setup_inputs)
#define BB   4
#define CF   256
#define CC   64
#define CP   80
#define HH   128   // hi-res
#define WW   128
#define KK   25
#define NPIX 16384 // 128*128

typedef __attribute__((ext_vector_type(8))) short short8v;
typedef __attribute__((ext_vector_type(4))) short short4v;
typedef __attribute__((ext_vector_type(4))) float f32x4;
typedef __attribute__((ext_vector_type(2))) float f32x2;

static __device__ __forceinline__ short f2bf(float f) {
  __hip_bfloat16 h = __float2bfloat16(f);
  return *reinterpret_cast<short*>(&h);
}

// =================== K1: compress (1x1 conv) via bf16 MFMA ==============
// guide[b][y][x][c] bf16 = sum_c' feat[b][c'][y][x] * wc[c][c'] + bc[c]
// grid 1024 = 4 b x 128 y x 2 x-halves (64 px). block 256 (4 waves).
// (unchanged — HBM-bound at ~its floor, ~13 us)
__global__ __launch_bounds__(256) void k_compress(
    const float* __restrict__ feat, const float* __restrict__ wc,
    const float* __restrict__ bc, const float* __restrict__ we,
    short* __restrict__ guide, short* __restrict__ web) {
  __shared__ short Al[32 * 520];  // [(cblk*4+lh)][o(64)*8], pad 512->520
  __shared__ short Bl[64 * 72];   // [px][c 0..63], stride 72
  const int tid = threadIdx.x;
  const int bx = blockIdx.x;
  const int b = bx >> 8;
  const int y = (bx >> 1) & 127;
  const int x0 = (bx & 1) << 6;

  // distributed web prestage: web[tap][kk pad32][c], zero for kk>=25
  {
    int j = bx * 256 + tid;
    if (j < 9 * 32 * 64) {
      int tap = j >> 11, kk = (j >> 6) & 31, c = j & 63;
      float v = (kk < KK) ? we[(kk * 64 + c) * 9 + tap] : 0.f;
      web[j] = f2bf(v);
    }
  }

  // convert wc (64x256 f32) -> Al in fragment order
#pragma unroll
  for (int t = 0; t < 8; ++t) {
    int idx = tid + t * 256;  // 0..2047
    int o = idx >> 5, c8 = idx & 31;
    const f32x4* src = (const f32x4*)(wc + o * CF + c8 * 8);
    f32x4 v0 = src[0], v1 = src[1];
    short8v h;
    h[0] = f2bf(v0.x); h[1] = f2bf(v0.y); h[2] = f2bf(v0.z); h[3] = f2bf(v0.w);
    h[4] = f2bf(v1.x); h[5] = f2bf(v1.y); h[6] = f2bf(v1.z); h[7] = f2bf(v1.w);
    int cblk = c8 >> 2, lh4 = c8 & 3;
    *(short8v*)(Al + (cblk * 4 + lh4) * 520 + o * 8) = h;
  }

  const int wave = tid >> 6, l = tid & 63;
  const int l15 = l & 15, lh = l >> 4;
  const int px_s = tid & 63;          // staging pixel
  const int c_s = (tid >> 6) << 4;    // staging channel offset (16/wave)
  const float* fb = feat + (size_t)b * CF * NPIX + y * WW + x0;

  f32x4 acc[4];
#pragma unroll
  for (int m = 0; m < 4; ++m) acc[m] = (f32x4){0.f, 0.f, 0.f, 0.f};

  for (int c0 = 0; c0 < CF; c0 += 64) {
    if (c0) __syncthreads();
    float v[16];
#pragma unroll
    for (int i = 0; i < 16; ++i)
      v[i] = fb[(size_t)(c0 + c_s + i) * NPIX + px_s];
    short8v h0, h1;
#pragma unroll
    for (int e = 0; e < 8; ++e) { h0[e] = f2bf(v[e]); h1[e] = f2bf(v[8 + e]); }
    *(short8v*)(Bl + px_s * 72 + c_s) = h0;
    *(short8v*)(Bl + px_s * 72 + c_s + 8) = h1;
    __syncthreads();  // Bl (and, first pass, Al) visible
#pragma unroll
    for (int ks = 0; ks < 64; ks += 32) {
      const int cblk = (c0 + ks) >> 5;
      short8v bfr = *(const short8v*)(Bl + (wave * 16 + l15) * 72 + ks + lh * 8);
#pragma unroll
      for (int m = 0; m < 4; ++m) {
        short8v a = *(const short8v*)(Al + (cblk * 4 + lh) * 520 +
                                      (m * 16 + l15) * 8);
        acc[m] = __builtin_amdgcn_mfma_f32_16x16x32_bf16(a, bfr, acc[m], 0, 0, 0);
      }
    }
  }

  // epilogue: +bias, cvt bf16, store [b][y][x][c]
  const int px = wave * 16 + l15;
  short* gb = guide + ((size_t)((b * HH + y) * WW + x0 + px)) * CC;
#pragma unroll
  for (int m = 0; m < 4; ++m) {
    short4v o;
#pragma unroll
    for (int r = 0; r < 4; ++r) {
      int c = m * 16 + lh * 4 + r;
      o[r] = f2bf(acc[m][r] + bc[c]);
    }
    *(short4v*)(gb + m * 16 + lh * 4) = o;
  }
}

// ===== K2: conv3x3 + bias + softmax via MFMA — 4x8 tiles, 128 thr =======
// (unchanged from round 9)
__global__ __launch_bounds__(128) void k_conv(
    const short* __restrict__ guide, const short* __restrict__ web,
    const float* __restrict__ be, float* __restrict__ maskq) {
  __shared__ short Gl[6 * 10 * 72];  // [y'(6)][x'(10)][c], stride 72
  const int tid = threadIdx.x;
  const int bx = blockIdx.x;
  const int b = bx >> 9;
  const int t = bx & 511;
  const int y0 = (t >> 4) << 2, x0 = (t & 15) << 3;
  const int wave = tid >> 6, l = tid & 63;
  const int l15 = l & 15, lh = l >> 4;

  // ---- stage guide halo tile 6x10 (zero-pad) ----
  for (int idx = tid; idx < 6 * 10 * 8; idx += 128) {
    int yp = idx / 80;
    int rem = idx - yp * 80;
    int xp = rem >> 3, cq = (rem & 7) << 3;
    int gy = y0 - 1 + yp, gx = x0 - 1 + xp;
    short8v v = {0, 0, 0, 0, 0, 0, 0, 0};
    if (gy >= 0 && gy < HH && gx >= 0 && gx < WW)
      v = *(const short8v*)(guide + ((size_t)((b * HH + gy) * WW + gx)) * CC + cq);
    *(short8v*)(Gl + (yp * 10 + xp) * 72 + cq) = v;
  }
  __syncthreads();

  // ---- conv MFMA: px = wave*16 + l15 -> (row, col) in 4x8 tile ----
  const int r_ = wave * 2 + (l15 >> 3);  // tile row 0..3
  const int cx = l15 & 7;                // tile col 0..7
  f32x4 acc0 = {0.f, 0.f, 0.f, 0.f}, acc1 = {0.f, 0.f, 0.f, 0.f};
#pragma unroll
  for (int tap = 0; tap < 9; ++tap) {
    const int dy = tap / 3, dx = tap - dy * 3;
#pragma unroll
    for (int ks = 0; ks < 64; ks += 32) {
      short8v a0 = *(const short8v*)(web + (tap * 32 + l15) * 64 + ks + lh * 8);
      short8v a1 =
          *(const short8v*)(web + (tap * 32 + 16 + l15) * 64 + ks + lh * 8);
      short8v bf = *(const short8v*)(Gl + ((r_ + dy) * 10 + cx + dx) * 72 +
                                     ks + lh * 8);
      acc0 = __builtin_amdgcn_mfma_f32_16x16x32_bf16(a0, bf, acc0, 0, 0, 0);
      acc1 = __builtin_amdgcn_mfma_f32_16x16x32_bf16(a1, bf, acc1, 0, 0, 0);
    }
  }

  // ---- bias + softmax over kk (25 vals in 4 lanes: xor 16,32) ----
  float sv[8];
#pragma unroll
  for (int r = 0; r < 4; ++r) {
    int kk0 = lh * 4 + r;            // 0..15, always < 25
    sv[r] = acc0[r] + be[kk0];
    int kk1 = 16 + lh * 4 + r;       // 16..31
    sv[4 + r] = (kk1 < KK) ? (acc1[r] + be[kk1]) : -1e30f;
  }
  float mx = sv[0];
#pragma unroll
  for (int i = 1; i < 8; ++i) mx = fmaxf(mx, sv[i]);
  mx = fmaxf(mx, __shfl_xor(mx, 16));
  mx = fmaxf(mx, __shfl_xor(mx, 32));
  float s = 0.f;
#pragma unroll
  for (int i = 0; i < 8; ++i) {
    sv[i] = __expf(sv[i] - mx);
    s += sv[i];
  }
  s += __shfl_xor(s, 16);
  s += __shfl_xor(s, 32);
  float inv = 1.f / s;

  // store: chunk q=lh (kk 4lh..) and q=4+lh (kk 16+4lh..), coalesced f32x4
  const int Y = y0 + r_, X = x0 + cx;
  const size_t pxoff = (size_t)(Y << 7) + X;
  f32x4 o0 = {sv[0] * inv, sv[1] * inv, sv[2] * inv, sv[3] * inv};
  *(f32x4*)(maskq + ((((size_t)(b * 7 + lh)) << 14) + pxoff) * 4) = o0;
  if (lh < 3) {  // chunks 4,5,6 (q=6 lanes 25..27 hold zeros)
    f32x4 o1 = {sv[4] * inv, sv[5] * inv, sv[6] * inv, sv[7] * inv};
    *(f32x4*)(maskq + ((((size_t)(b * 7 + 4 + lh)) << 14) + pxoff) * 4) = o1;
  }
}

// ========== K3 v5: CARAFE — 8x32 tiles, full-line coalesced stores ======
// grid 5120 = cg(20) x [ b(4) x ty(16) x tx(4) ].  block 256 = 4 ch-waves
// x 64 quads (4 qy x 16 qx).  Thread = one 2x2 hi-px quad (shares one 5x5
// lo patch) x 1 channel: m[4][25] in regs (launch_bounds(256,3): no spill),
// p via conflict-free LDS [c4][r8][cl24].  Stores: 16 lanes x f32x2 = 128B
// full lines (vs 32B segments in all prior rounds).
__global__ __launch_bounds__(256, 3) void k_carafe5(
    const float* __restrict__ pred, const float* __restrict__ maskq,
    float* __restrict__ out) {
  __shared__ float Pl[4 * 8 * 24];  // [c][r][cl pad 20->24] = 3 KB
  const int tid = threadIdx.x;
  const int bx = blockIdx.x;
  const int cg = bx >> 8;          // 0..19 -> 4-channel group
  const int inner = bx & 255;
  const int b = (inner >> 6) & 3;
  const int ty0 = (inner >> 2) & 15;
  const int tx0 = inner & 3;
  const int Y0 = ty0 << 3, X0 = tx0 << 5;

  const int qx = tid & 15;         // quad col 0..15
  const int qy = (tid >> 4) & 3;   // quad row 0..3
  const int cl_ch = tid >> 6;      // channel lane 0..3 (one per wave)
  const int ch = cg * 4 + cl_ch;

  // ---- stage Pl: 4 ch x 8 r x 20 cl, reflect-padded ----
  const int ylo = (Y0 >> 1) - 2, xlo = (X0 >> 1) - 2;
#pragma unroll
  for (int it = 0; it < 3; ++it) {
    int idx = it * 256 + tid;
    if (idx < 640) {
      int c = idx / 160;
      int rem = idx - c * 160;
      int r = rem / 20;
      int cl = rem - r * 20;
      int ry = ylo + r;
      ry = ry < 0 ? -ry : (ry > 63 ? 126 - ry : ry);
      int rx = xlo + cl;
      rx = rx < 0 ? -rx : (rx > 63 ? 126 - rx : rx);
      Pl[(c * 8 + r) * 24 + cl] =
          pred[(((size_t)(b * CP + cg * 4 + c)) << 12) + (ry << 6) + rx];
    }
  }

  // ---- quad masks -> registers (overlaps staging latency) ----
  float m[4][KK];
#pragma unroll
  for (int dy = 0; dy < 2; ++dy)
#pragma unroll
    for (int dx = 0; dx < 2; ++dx) {
      const int Y = Y0 + qy * 2 + dy, X = X0 + qx * 2 + dx;
      const size_t pxoff = (size_t)(Y << 7) + X;
      const int k = dy * 2 + dx;
#pragma unroll
      for (int q = 0; q < 7; ++q) {
        f32x4 mv = *(const f32x4*)(maskq +
                                   ((((size_t)(b * 7 + q)) << 14) + pxoff) * 4);
#pragma unroll
        for (int e = 0; e < 4; ++e) {
          int kk = q * 4 + e;
          if (kk < KK) m[k][kk] = mv[e];
        }
      }
    }
  __syncthreads();  // Pl ready

  // ---- carafe: 25 LDS reads, 100 FMA, quad shares the patch ----
  float acc[4] = {0.f, 0.f, 0.f, 0.f};
  const float* P0 = Pl + (cl_ch * 8 + qy) * 24 + qx;
#pragma unroll
  for (int i = 0; i < 5; ++i)
#pragma unroll
    for (int j = 0; j < 5; ++j) {
      float p = P0[i * 24 + j];
      const int kk = i * 5 + j;
      acc[0] += p * m[0][kk];
      acc[1] += p * m[1][kk];
      acc[2] += p * m[2][kk];
      acc[3] += p * m[3][kk];
    }

  // ---- stores: per row, 16 qx lanes x 8B = 128B contiguous ----
  float* ob = out + (((size_t)(b * CP + ch)) << 14) + (Y0 + qy * 2) * WW +
              X0 + qx * 2;
  f32x2 v0 = {acc[0], acc[1]};
  f32x2 v1 = {acc[2], acc[3]};
  *(f32x2*)ob = v0;
  *(f32x2*)(ob + WW) = v1;
}

extern "C" void kernel_launch(void* const* d_in, const int* in_sizes, int n_in,
                              void* d_out, int out_size, void* d_ws,
                              size_t ws_size, hipStream_t stream) {
  (void)in_sizes; (void)n_in; (void)out_size; (void)ws_size;
  const float* pred = (const float*)d_in[0];  // (4,80,64,64)
  const float* feat = (const float*)d_in[1];  // (4,256,128,128)
  const float* wc   = (const float*)d_in[2];  // (64,256)
  const float* bc   = (const float*)d_in[3];  // (64)
  const float* we   = (const float*)d_in[4];  // (25,64,3,3)
  const float* be   = (const float*)d_in[5];  // (25)
  float* out = (float*)d_out;                 // (4,80,128,128)

  char* ws = (char*)d_ws;
  short* guide = (short*)ws;                    // 8,388,608 B bf16 [b][y][x][c]
  short* web   = (short*)(ws + 8388608);        // 36,864 B bf16 [tap][kk32][c]
  float* maskq = (float*)(ws + 8388608 + 36864);// 7,340,032 B f32 [b][7][Y][X][4]

  hipLaunchKernelGGL(k_compress, dim3(1024), dim3(256), 0, stream,
                     feat, wc, bc, we, guide, web);
  hipLaunchKernelGGL(k_conv, dim3(2048), dim3(128), 0, stream,
                     guide, web, be, maskq);
  hipLaunchKernelGGL(k_carafe5, dim3(5120), dim3(256), 0, stream,
                     pred, maskq, out);
}

// Round 11
// 60.192 us; speedup vs baseline: 1.1110x; 1.1110x over previous
//
#include <hip/hip_runtime.h>
#include <hip/hip_bf16.h>

// Problem constants (fixed by setup_inputs)
#define BB   4
#define CF   256
#define CC   64
#define CP   80
#define HH   128   // hi-res
#define WW   128
#define KK   25
#define NPIX 16384 // 128*128

typedef __attribute__((ext_vector_type(8))) short short8v;
typedef __attribute__((ext_vector_type(4))) short short4v;
typedef __attribute__((ext_vector_type(4))) float f32x4;
typedef __attribute__((ext_vector_type(2))) float f32x2;

static __device__ __forceinline__ short f2bf(float f) {
  __hip_bfloat16 h = __float2bfloat16(f);
  return *reinterpret_cast<short*>(&h);
}

// =================== K1: compress (1x1 conv) via bf16 MFMA ==============
// (byte-identical to round 9 — HBM-bound at ~its floor, ~13 us)
__global__ __launch_bounds__(256) void k_compress(
    const float* __restrict__ feat, const float* __restrict__ wc,
    const float* __restrict__ bc, const float* __restrict__ we,
    short* __restrict__ guide, short* __restrict__ web) {
  __shared__ short Al[32 * 520];  // [(cblk*4+lh)][o(64)*8], pad 512->520
  __shared__ short Bl[64 * 72];   // [px][c 0..63], stride 72
  const int tid = threadIdx.x;
  const int bx = blockIdx.x;
  const int b = bx >> 8;
  const int y = (bx >> 1) & 127;
  const int x0 = (bx & 1) << 6;

  // distributed web prestage: web[tap][kk pad32][c], zero for kk>=25
  {
    int j = bx * 256 + tid;
    if (j < 9 * 32 * 64) {
      int tap = j >> 11, kk = (j >> 6) & 31, c = j & 63;
      float v = (kk < KK) ? we[(kk * 64 + c) * 9 + tap] : 0.f;
      web[j] = f2bf(v);
    }
  }

  // convert wc (64x256 f32) -> Al in fragment order
#pragma unroll
  for (int t = 0; t < 8; ++t) {
    int idx = tid + t * 256;  // 0..2047
    int o = idx >> 5, c8 = idx & 31;
    const f32x4* src = (const f32x4*)(wc + o * CF + c8 * 8);
    f32x4 v0 = src[0], v1 = src[1];
    short8v h;
    h[0] = f2bf(v0.x); h[1] = f2bf(v0.y); h[2] = f2bf(v0.z); h[3] = f2bf(v0.w);
    h[4] = f2bf(v1.x); h[5] = f2bf(v1.y); h[6] = f2bf(v1.z); h[7] = f2bf(v1.w);
    int cblk = c8 >> 2, lh4 = c8 & 3;
    *(short8v*)(Al + (cblk * 4 + lh4) * 520 + o * 8) = h;
  }

  const int wave = tid >> 6, l = tid & 63;
  const int l15 = l & 15, lh = l >> 4;
  const int px_s = tid & 63;          // staging pixel
  const int c_s = (tid >> 6) << 4;    // staging channel offset (16/wave)
  const float* fb = feat + (size_t)b * CF * NPIX + y * WW + x0;

  f32x4 acc[4];
#pragma unroll
  for (int m = 0; m < 4; ++m) acc[m] = (f32x4){0.f, 0.f, 0.f, 0.f};

  for (int c0 = 0; c0 < CF; c0 += 64) {
    if (c0) __syncthreads();
    float v[16];
#pragma unroll
    for (int i = 0; i < 16; ++i)
      v[i] = fb[(size_t)(c0 + c_s + i) * NPIX + px_s];
    short8v h0, h1;
#pragma unroll
    for (int e = 0; e < 8; ++e) { h0[e] = f2bf(v[e]); h1[e] = f2bf(v[8 + e]); }
    *(short8v*)(Bl + px_s * 72 + c_s) = h0;
    *(short8v*)(Bl + px_s * 72 + c_s + 8) = h1;
    __syncthreads();  // Bl (and, first pass, Al) visible
#pragma unroll
    for (int ks = 0; ks < 64; ks += 32) {
      const int cblk = (c0 + ks) >> 5;
      short8v bfr = *(const short8v*)(Bl + (wave * 16 + l15) * 72 + ks + lh * 8);
#pragma unroll
      for (int m = 0; m < 4; ++m) {
        short8v a = *(const short8v*)(Al + (cblk * 4 + lh) * 520 +
                                      (m * 16 + l15) * 8);
        acc[m] = __builtin_amdgcn_mfma_f32_16x16x32_bf16(a, bfr, acc[m], 0, 0, 0);
      }
    }
  }

  // epilogue: +bias, cvt bf16, store [b][y][x][c]
  const int px = wave * 16 + l15;
  short* gb = guide + ((size_t)((b * HH + y) * WW + x0 + px)) * CC;
#pragma unroll
  for (int m = 0; m < 4; ++m) {
    short4v o;
#pragma unroll
    for (int r = 0; r < 4; ++r) {
      int c = m * 16 + lh * 4 + r;
      o[r] = f2bf(acc[m][r] + bc[c]);
    }
    *(short4v*)(gb + m * 16 + lh * 4) = o;
  }
}

// ===== K2: conv3x3 + bias + softmax via MFMA — 4x8 tiles, 128 thr =======
// (byte-identical to round 9)
__global__ __launch_bounds__(128) void k_conv(
    const short* __restrict__ guide, const short* __restrict__ web,
    const float* __restrict__ be, float* __restrict__ maskq) {
  __shared__ short Gl[6 * 10 * 72];  // [y'(6)][x'(10)][c], stride 72
  const int tid = threadIdx.x;
  const int bx = blockIdx.x;
  const int b = bx >> 9;
  const int t = bx & 511;
  const int y0 = (t >> 4) << 2, x0 = (t & 15) << 3;
  const int wave = tid >> 6, l = tid & 63;
  const int l15 = l & 15, lh = l >> 4;

  // ---- stage guide halo tile 6x10 (zero-pad) ----
  for (int idx = tid; idx < 6 * 10 * 8; idx += 128) {
    int yp = idx / 80;
    int rem = idx - yp * 80;
    int xp = rem >> 3, cq = (rem & 7) << 3;
    int gy = y0 - 1 + yp, gx = x0 - 1 + xp;
    short8v v = {0, 0, 0, 0, 0, 0, 0, 0};
    if (gy >= 0 && gy < HH && gx >= 0 && gx < WW)
      v = *(const short8v*)(guide + ((size_t)((b * HH + gy) * WW + gx)) * CC + cq);
    *(short8v*)(Gl + (yp * 10 + xp) * 72 + cq) = v;
  }
  __syncthreads();

  // ---- conv MFMA: px = wave*16 + l15 -> (row, col) in 4x8 tile ----
  const int r_ = wave * 2 + (l15 >> 3);  // tile row 0..3
  const int cx = l15 & 7;                // tile col 0..7
  f32x4 acc0 = {0.f, 0.f, 0.f, 0.f}, acc1 = {0.f, 0.f, 0.f, 0.f};
#pragma unroll
  for (int tap = 0; tap < 9; ++tap) {
    const int dy = tap / 3, dx = tap - dy * 3;
#pragma unroll
    for (int ks = 0; ks < 64; ks += 32) {
      short8v a0 = *(const short8v*)(web + (tap * 32 + l15) * 64 + ks + lh * 8);
      short8v a1 =
          *(const short8v*)(web + (tap * 32 + 16 + l15) * 64 + ks + lh * 8);
      short8v bf = *(const short8v*)(Gl + ((r_ + dy) * 10 + cx + dx) * 72 +
                                     ks + lh * 8);
      acc0 = __builtin_amdgcn_mfma_f32_16x16x32_bf16(a0, bf, acc0, 0, 0, 0);
      acc1 = __builtin_amdgcn_mfma_f32_16x16x32_bf16(a1, bf, acc1, 0, 0, 0);
    }
  }

  // ---- bias + softmax over kk (25 vals in 4 lanes: xor 16,32) ----
  float sv[8];
#pragma unroll
  for (int r = 0; r < 4; ++r) {
    int kk0 = lh * 4 + r;            // 0..15, always < 25
    sv[r] = acc0[r] + be[kk0];
    int kk1 = 16 + lh * 4 + r;       // 16..31
    sv[4 + r] = (kk1 < KK) ? (acc1[r] + be[kk1]) : -1e30f;
  }
  float mx = sv[0];
#pragma unroll
  for (int i = 1; i < 8; ++i) mx = fmaxf(mx, sv[i]);
  mx = fmaxf(mx, __shfl_xor(mx, 16));
  mx = fmaxf(mx, __shfl_xor(mx, 32));
  float s = 0.f;
#pragma unroll
  for (int i = 0; i < 8; ++i) {
    sv[i] = __expf(sv[i] - mx);
    s += sv[i];
  }
  s += __shfl_xor(s, 16);
  s += __shfl_xor(s, 32);
  float inv = 1.f / s;

  // store: chunk q=lh (kk 4lh..) and q=4+lh (kk 16+4lh..), coalesced f32x4
  const int Y = y0 + r_, X = x0 + cx;
  const size_t pxoff = (size_t)(Y << 7) + X;
  f32x4 o0 = {sv[0] * inv, sv[1] * inv, sv[2] * inv, sv[3] * inv};
  *(f32x4*)(maskq + ((((size_t)(b * 7 + lh)) << 14) + pxoff) * 4) = o0;
  if (lh < 3) {  // chunks 4,5,6 (q=6 lanes 25..27 hold zeros)
    f32x4 o1 = {sv[4] * inv, sv[5] * inv, sv[6] * inv, sv[7] * inv};
    *(f32x4*)(maskq + ((((size_t)(b * 7 + 4 + lh)) << 14) + pxoff) * 4) = o1;
  }
}

// ===== K3 v6: CARAFE — 4x32 tile x ALL 80 ch, quad-share, LDS masks =====
// grid 512 = b(4) x ty(32, 4-row tiles) x tx(4, 32-col tiles). block 512.
// Thread = quad (qy 0..1, qx 0..15) x ch-slot s (0..15; ch {2s,2s+1,
// 2s+32,2s+33,64+s}).  m[4][25] = 100 VGPR (quad-shared patch -> LDS
// traffic halved vs pair).  Masks staged to LDS once (7.3 MB total reads).
// Stores: 16 qx-lanes x f32x2 = 128B full lines.
__global__ __launch_bounds__(512, 2) void k_carafe6(
    const float* __restrict__ pred, const float* __restrict__ maskq,
    float* __restrict__ out) {
  __shared__ float Pl[120 * 84];   // [cell = r(6)*20+cl][ch pad 80->84] 40.3 KB
  __shared__ float Msk[4 * 900];   // [y][x*28 + q*4 + e], row pad 896->900
  const int tid = threadIdx.x;
  const int bx = blockIdx.x;
  const int b = bx >> 7;
  const int ty = (bx >> 2) & 31;
  const int tx = bx & 3;
  const int Y0 = ty << 2, X0 = tx << 5;

  // ---- stage Pl: 80 ch x 6 rows x 20 cols, reflect-padded, ch-innermost --
  const int ylo = (Y0 >> 1) - 2, xlo = (X0 >> 1) - 2;
  for (int idx = tid; idx < 9600; idx += 512) {
    int c = idx / 120;
    int cell = idx - c * 120;
    int r = cell / 20, cl = cell - r * 20;
    int ry = ylo + r;
    ry = ry < 0 ? -ry : (ry > 63 ? 126 - ry : ry);
    int rx = xlo + cl;
    rx = rx < 0 ? -rx : (rx > 63 ? 126 - rx : rx);
    Pl[cell * 84 + c] = pred[(((size_t)(b * CP + c)) << 12) + (ry << 6) + rx];
  }
  // ---- stage Msk: 7 chunks x 4 rows x 32 cols of f32x4, coalesced ----
  for (int idx = tid; idx < 896; idx += 512) {
    int q = idx >> 7;
    int y = (idx >> 5) & 3;
    int x = idx & 31;
    f32x4 v = *(const f32x4*)(maskq + ((((size_t)(b * 7 + q)) << 14) +
                                       ((size_t)((Y0 + y) << 7)) + X0 + x) * 4);
    *(f32x4*)(&Msk[y * 900 + x * 28 + q * 4]) = v;
  }
  __syncthreads();

  const int qx = tid & 15;
  const int qy = (tid >> 4) & 1;
  const int s = tid >> 5;  // 0..15

  // ---- quad masks -> registers (LDS, slots broadcast) ----
  float m[4][KK];
#pragma unroll
  for (int dy = 0; dy < 2; ++dy)
#pragma unroll
    for (int dx = 0; dx < 2; ++dx) {
      const float* mb = &Msk[(2 * qy + dy) * 900 + (2 * qx + dx) * 28];
      const int k = dy * 2 + dx;
#pragma unroll
      for (int q = 0; q < 7; ++q) {
        f32x4 mv = *(const f32x4*)(mb + q * 4);
#pragma unroll
        for (int e = 0; e < 4; ++e) {
          int kk = q * 4 + e;
          if (kk < KK) m[k][kk] = mv[e];
        }
      }
    }

  // ---- carafe: 25 cells x (5 ch x 4 px) FMAs, one patch per quad ----
  float acc[5][4];
#pragma unroll
  for (int cc = 0; cc < 5; ++cc)
#pragma unroll
    for (int k = 0; k < 4; ++k) acc[cc][k] = 0.f;

#pragma unroll
  for (int i = 0; i < 5; ++i)
#pragma unroll
    for (int j = 0; j < 5; ++j) {
      const float* P = &Pl[((qy + i) * 20 + qx + j) * 84];
      f32x2 p01 = *(const f32x2*)(P + 2 * s);
      f32x2 p23 = *(const f32x2*)(P + 2 * s + 32);
      float p4 = P[64 + s];
      const int kk = i * 5 + j;
#pragma unroll
      for (int k = 0; k < 4; ++k) {
        float mk = m[k][kk];
        acc[0][k] += p01.x * mk;
        acc[1][k] += p01.y * mk;
        acc[2][k] += p23.x * mk;
        acc[3][k] += p23.y * mk;
        acc[4][k] += p4 * mk;
      }
    }

  // ---- stores: per (slot,qy,dy) row, 16 qx lanes x 8B = 128B lines ----
  const int chs[5] = {2 * s, 2 * s + 1, 2 * s + 32, 2 * s + 33, 64 + s};
#pragma unroll
  for (int cc = 0; cc < 5; ++cc) {
    float* ob = out + (((size_t)(b * CP + chs[cc])) << 14);
#pragma unroll
    for (int dy = 0; dy < 2; ++dy) {
      f32x2 v = {acc[cc][dy * 2 + 0], acc[cc][dy * 2 + 1]};
      *(f32x2*)(ob + (Y0 + 2 * qy + dy) * WW + X0 + 2 * qx) = v;
    }
  }
}

extern "C" void kernel_launch(void* const* d_in, const int* in_sizes, int n_in,
                              void* d_out, int out_size, void* d_ws,
                              size_t ws_size, hipStream_t stream) {
  (void)in_sizes; (void)n_in; (void)out_size; (void)ws_size;
  const float* pred = (const float*)d_in[0];  // (4,80,64,64)
  const float* feat = (const float*)d_in[1];  // (4,256,128,128)
  const float* wc   = (const float*)d_in[2];  // (64,256)
  const float* bc   = (const float*)d_in[3];  // (64)
  const float* we   = (const float*)d_in[4];  // (25,64,3,3)
  const float* be   = (const float*)d_in[5];  // (25)
  float* out = (float*)d_out;                 // (4,80,128,128)

  char* ws = (char*)d_ws;
  short* guide = (short*)ws;                    // 8,388,608 B bf16 [b][y][x][c]
  short* web   = (short*)(ws + 8388608);        // 36,864 B bf16 [tap][kk32][c]
  float* maskq = (float*)(ws + 8388608 + 36864);// 7,340,032 B f32 [b][7][Y][X][4]

  hipLaunchKernelGGL(k_compress, dim3(1024), dim3(256), 0, stream,
                     feat, wc, bc, we, guide, web);
  hipLaunchKernelGGL(k_conv, dim3(2048), dim3(128), 0, stream,
                     guide, web, be, maskq);
  hipLaunchKernelGGL(k_carafe6, dim3(512), dim3(512), 0, stream,
                     pred, maskq, out);
}